// Round 12
// baseline (308.968 us; speedup 1.0000x reference)
//
#include <hip/hip_runtime.h>

// PFNLayer feature augmentation (PointPillars), MI355X.
// R7 post-mortem: LDS-staged linear stores bought 309->302us; kernel est
// ~83us vs ~55us floor. This round removes the LDS round-trip entirely:
// 8 lanes per pillar, each thread owns 4 consecutive point slots ->
// float4 loads, 3-stage width-8 shuffle reduce, 9x float4 stores
// (8 full 128B lines per wave per store instr). No LDS, no barrier.
// Layout: d_out = [coors_as_float (P*4)] ++ [features (P*9*32)].
//
// Reference semantics replicated exactly:
//  - mean = sum over ALL 32 slots (padding included) / true count
//  - cy uses X_OFFSET (upstream bug, replicated)
//  - padded slots zeroed in the 9-channel output

#define X_VOXEL 0.16f
#define Y_VOXEL 0.16f
#define X_OFFSET 0.08f   // voxel/2 + range0; used for BOTH x and y (ref bug)
#define MAX_PTS 32

__global__ __launch_bounds__(256) void pfn_kernel(
    const float4* __restrict__ pillars,   // (P, 32) as float4 per point
    const int*    __restrict__ coors,     // (P, 4)
    const int*    __restrict__ npoints,   // (P,)
    float*        __restrict__ out_coors, // (P, 4) as float (value-converted)
    float*        __restrict__ out_feat,  // (P, 9, 32)
    int P)
{
    int tid = blockIdx.x * blockDim.x + threadIdx.x;
    int p   = tid >> 3;                   // pillar (8 lanes per pillar)
    int g   = tid & 7;                    // slot group: owns slots 4g..4g+3

    // coors pass-through: first 32 threads of each block handle the block's
    // 32 pillars -> 512B contiguous int4 load + float4 store.
    int cbase = blockIdx.x * 32;
    if (threadIdx.x < 32 && cbase + threadIdx.x < P) {
        int4 c4 = ((const int4*)coors)[cbase + threadIdx.x];
        ((float4*)out_coors)[cbase + threadIdx.x] =
            make_float4((float)c4.x, (float)c4.y, (float)c4.z, (float)c4.w);
    }

    if (p >= P) return;

    // 4 float4 loads: thread covers 64B contiguous; wave covers 8 pillars.
    const float4* src = pillars + (size_t)p * MAX_PTS + 4 * g;
    float4 pt0 = src[0], pt1 = src[1], pt2 = src[2], pt3 = src[3];

    // Mean over ALL 32 slots: local 4-point sum, then width-8 butterfly.
    float sx = pt0.x + pt1.x + pt2.x + pt3.x;
    float sy = pt0.y + pt1.y + pt2.y + pt3.y;
    float sz = pt0.z + pt1.z + pt2.z + pt3.z;
    #pragma unroll
    for (int off = 4; off > 0; off >>= 1) {
        sx += __shfl_xor(sx, off, 8);
        sy += __shfl_xor(sy, off, 8);
        sz += __shfl_xor(sz, off, 8);
    }

    int np = npoints[p];
    float n  = (float)np;
    float mx = sx / n, my = sy / n, mz = sz / n;   // IEEE div, matches jnp

    // cx, cy: lane g reads coors[p*4 + (g&3)], broadcast idx 1,2 within group.
    int cv = coors[p * 4 + (g & 3)];
    float cx = (float)__shfl(cv, 1, 8) * X_VOXEL + X_OFFSET;
    float cy = (float)__shfl(cv, 2, 8) * Y_VOXEL + X_OFFSET;  // ref bug

    // Per-slot masks (slot index 4g+i vs true count).
    float m0 = (4 * g + 0 < np) ? 1.0f : 0.0f;
    float m1 = (4 * g + 1 < np) ? 1.0f : 0.0f;
    float m2 = (4 * g + 2 < np) ? 1.0f : 0.0f;
    float m3 = (4 * g + 3 < np) ? 1.0f : 0.0f;

    // 9 channel float4 stores; each wave store instr = 8 full 128B lines.
    float* o = out_feat + (size_t)p * 288 + 4 * g;
    #define ST(c, e) ((float4*)(o + (c) * 32))[0] = make_float4( \
        (pt0.e) * m0, (pt1.e) * m1, (pt2.e) * m2, (pt3.e) * m3)

    float4 ox = make_float4(pt0.x - cx, pt1.x - cx, pt2.x - cx, pt3.x - cx);
    float4 oy = make_float4(pt0.y - cy, pt1.y - cy, pt2.y - cy, pt3.y - cy);
    ox.x *= m0; ox.y *= m1; ox.z *= m2; ox.w *= m3;
    oy.x *= m0; oy.y *= m1; oy.z *= m2; oy.w *= m3;

    ((float4*)(o +   0))[0] = ox;                       // ch0: off_x
    ((float4*)(o +  32))[0] = oy;                       // ch1: off_y
    ST(2, z);                                           // ch2: z
    ST(3, w);                                           // ch3: intensity
    ((float4*)(o + 128))[0] = make_float4((pt0.x - mx) * m0, (pt1.x - mx) * m1,
                                          (pt2.x - mx) * m2, (pt3.x - mx) * m3);
    ((float4*)(o + 160))[0] = make_float4((pt0.y - my) * m0, (pt1.y - my) * m1,
                                          (pt2.y - my) * m2, (pt3.y - my) * m3);
    ((float4*)(o + 192))[0] = make_float4((pt0.z - mz) * m0, (pt1.z - mz) * m1,
                                          (pt2.z - mz) * m2, (pt3.z - mz) * m3);
    ((float4*)(o + 224))[0] = ox;                       // ch7: off_x again
    ((float4*)(o + 256))[0] = oy;                       // ch8: off_y again
    #undef ST
}

extern "C" void kernel_launch(void* const* d_in, const int* in_sizes, int n_in,
                              void* d_out, int out_size, void* d_ws, size_t ws_size,
                              hipStream_t stream) {
    const float* pillars = (const float*)d_in[0];
    const int*   coors   = (const int*)d_in[1];
    const int*   npoints = (const int*)d_in[2];
    int P = in_sizes[2];                       // 200000

    float* out       = (float*)d_out;
    float* out_coors = out;                    // first P*4 elements
    float* out_feat  = out + (size_t)P * 4;    // then P*9*32

    const int threads = 256;                   // 32 pillars / block
    long long total = (long long)P * 8;        // 8 threads per pillar
    int grid = (int)((total + threads - 1) / threads);   // 6250 blocks
    pfn_kernel<<<grid, threads, 0, stream>>>(
        (const float4*)pillars, coors, npoints, out_coors, out_feat, P);
}

// Round 20
// 291.171 us; speedup vs baseline: 1.0611x; 1.0611x over previous
//
#include <hip/hip_runtime.h>

// PFNLayer feature augmentation (PointPillars), MI355X.
// Measured A/B trail: R6 no-LDS dword channel stores 309.3; R12 no-LDS
// float4 channel stores 309.0 (width irrelevant); R7 LDS-staged LINEAR
// stream stores 302.0 (linearity is the lever). This round = R7 structure
// + nontemporal load/store hints (read-once/write-once streams both >> L2).
// R15 compile fix: nontemporal builtins need clang ext_vector_type, not
// HIP_vector_type -> use f32x4 for all nt accesses.
// Layout: d_out = [coors_as_float (P*4)] ++ [features (P*9*32)].
//
// Reference semantics replicated exactly:
//  - mean = sum over ALL 32 slots (padding included) / true count
//  - cy uses X_OFFSET (upstream bug, replicated)
//  - padded slots zeroed in the 9-channel output

#define X_VOXEL 0.16f
#define Y_VOXEL 0.16f
#define X_OFFSET 0.08f   // voxel/2 + range0; used for BOTH x and y (ref bug)
#define MAX_PTS 32
#define PPB 8            // pillars per 256-thread block

typedef float f32x4 __attribute__((ext_vector_type(4)));

__global__ __launch_bounds__(256) void pfn_kernel(
    const f32x4* __restrict__ pillars,    // (P, 32) as 16B per point
    const int*   __restrict__ coors,      // (P, 4)
    const int*   __restrict__ npoints,    // (P,)
    float*       __restrict__ out_coors,  // (P, 4) as float (value-converted)
    float*       __restrict__ out_feat,   // (P, 9, 32)
    int P)
{
    __shared__ float lds[PPB * 9 * MAX_PTS];   // 9216 B per block

    int tid  = threadIdx.x;
    int lane = tid & 31;
    int hw   = tid >> 5;                  // half-wave id in block = local pillar
    int base = blockIdx.x * PPB;
    int pillar = base + hw;

    if (pillar < P) {
        // Coalesced 16B/lane load, read-once -> nontemporal.
        f32x4 pt = __builtin_nontemporal_load(
            pillars + (size_t)pillar * MAX_PTS + lane);

        // Sum xyz over ALL 32 slots (reference sums padded slots too).
        float sx = pt.x, sy = pt.y, sz = pt.z;
        #pragma unroll
        for (int off = 16; off > 0; off >>= 1) {
            sx += __shfl_xor(sx, off, 32);
            sy += __shfl_xor(sy, off, 32);
            sz += __shfl_xor(sz, off, 32);
        }

        int np = npoints[pillar];
        float n  = (float)np;
        float mx = sx / n, my = sy / n, mz = sz / n;   // IEEE div, matches jnp

        int cv = coors[pillar * 4 + (lane & 3)];
        float cx = (float)__shfl(cv, 1, 32) * X_VOXEL + X_OFFSET;
        float cy = (float)__shfl(cv, 2, 32) * Y_VOXEL + X_OFFSET;  // ref bug

        float m  = (lane < np) ? 1.0f : 0.0f;  // zero padded slots
        float f0 = (pt.x - cx) * m;   // off_x
        float f1 = (pt.y - cy) * m;   // off_y

        // Stage [pillar][channel][lane]; 2-way bank alias only (free, m136).
        float* l = lds + hw * 288 + lane;
        l[  0] = f0;
        l[ 32] = f1;
        l[ 64] = pt.z * m;
        l[ 96] = pt.w * m;
        l[128] = (pt.x - mx) * m;
        l[160] = (pt.y - my) * m;
        l[192] = (pt.z - mz) * m;
        l[224] = f0;
        l[256] = f1;
    }
    __syncthreads();

    // Linear f32x4 write-out: 9216B contiguous per block, write-once ->
    // nontemporal (same stream shape as the 6.4 TB/s fill kernel).
    int npil = P - base; if (npil > PPB) npil = PPB;
    int nf4  = npil * 72;                       // 72 x 16B per pillar
    f32x4* dst = (f32x4*)(out_feat + (size_t)base * 288);
    const f32x4* src = (const f32x4*)lds;
    for (int i = tid; i < nf4; i += 256)
        __builtin_nontemporal_store(src[i], dst + i);

    // coors pass-through: one 16B store per pillar, one 128B line per block.
    if (tid < npil) {
        int4 c4 = ((const int4*)coors)[base + tid];
        f32x4 cf = { (float)c4.x, (float)c4.y, (float)c4.z, (float)c4.w };
        __builtin_nontemporal_store(cf, ((f32x4*)out_coors) + base + tid);
    }
}

extern "C" void kernel_launch(void* const* d_in, const int* in_sizes, int n_in,
                              void* d_out, int out_size, void* d_ws, size_t ws_size,
                              hipStream_t stream) {
    const float* pillars = (const float*)d_in[0];
    const int*   coors   = (const int*)d_in[1];
    const int*   npoints = (const int*)d_in[2];
    int P = in_sizes[2];                       // 200000

    float* out       = (float*)d_out;
    float* out_coors = out;                    // first P*4 elements
    float* out_feat  = out + (size_t)P * 4;    // then P*9*32

    const int threads = 256;                   // 8 pillars / block
    int grid = (P + PPB - 1) / PPB;            // 25000 blocks
    pfn_kernel<<<grid, threads, 0, stream>>>(
        (const f32x4*)pillars, coors, npoints, out_coors, out_feat, P);
}